// Round 1
// baseline (105.775 us; speedup 1.0000x reference)
//
#include <hip/hip_runtime.h>
#include <hip/hip_bf16.h>

// ChamferDistanceLoss: pred/target (4,1,64,64,64) fp32.
// Per batch: select first 10000 active voxels (>0.5, ascending flat idx),
// normalize coords v/63*2-1, bidirectional chamfer (mean min sq dist), mean over batch.

#define NVOX      262144     // 64^3
#define NCHUNK    256        // chunks per cloud (1024 elems each)
#define MAXPTS    10000
#define PTS_PAD   10240      // padded point stride
#define NCLOUD    8          // 4 batches x {pred,target}
#define NTASK     8          // 4 batches x 2 directions
#define NSEG      16
#define SEGLEN    640        // NSEG*SEGLEN = PTS_PAD
#define NQ        10         // queries per thread
#define QB        4          // query blocks per task (QB*256*NQ = PTS_PAD)
#define NRB       40         // reduce blocks per task (NRB*256 = PTS_PAD)
#define SCALE     (2.0f/63.0f)

// ---------------- workspace layout (bytes) ----------------
#define WS_TOTALS   0          // 8 ints
#define WS_COUNTS   1024       // 8*256 ints
#define WS_OFFSETS  16384      // 8*256 ints
#define WS_PTS      32768      // 8 clouds * 3 * PTS_PAD floats = 983040 B
#define WS_PARTIAL  1048576    // 8 tasks * 16 segs * PTS_PAD floats = 5242880 B
#define WS_BSUM     6291456    // 8 tasks * 40 floats
#define WS_NEED     (6291456 + 8*NRB*4)

__device__ __forceinline__ const float* cloud_src(const float* pred, const float* tgt, int cloud) {
    const float* base = (cloud & 1) ? tgt : pred;
    return base + (size_t)(cloud >> 1) * NVOX;
}

// ---- Kernel 1: per-chunk active counts -------------------------------------
__global__ void k_count(const float* __restrict__ pred, const float* __restrict__ tgt,
                        int* __restrict__ counts) {
    int cloud = blockIdx.x >> 8;
    int chunk = blockIdx.x & 255;
    int t = threadIdx.x;
    const float* src = cloud_src(pred, tgt, cloud) + chunk * 1024;
    float4 v = reinterpret_cast<const float4*>(src)[t];
    int cnt = (v.x > 0.5f) + (v.y > 0.5f) + (v.z > 0.5f) + (v.w > 0.5f);
    __shared__ int s[256];
    s[t] = cnt; __syncthreads();
    for (int o = 128; o > 0; o >>= 1) {
        if (t < o) s[t] += s[t + o];
        __syncthreads();
    }
    if (t == 0) counts[cloud * NCHUNK + chunk] = s[0];
}

// ---- Kernel 2: exclusive scan of chunk counts per cloud --------------------
__global__ void k_scan(const int* __restrict__ counts, int* __restrict__ offsets,
                       int* __restrict__ totals) {
    int cloud = blockIdx.x;
    int t = threadIdx.x;
    int c = counts[cloud * NCHUNK + t];
    __shared__ int s[256];
    s[t] = c; __syncthreads();
    for (int o = 1; o < 256; o <<= 1) {
        int v = (t >= o) ? s[t - o] : 0;
        __syncthreads();
        s[t] += v;
        __syncthreads();
    }
    offsets[cloud * NCHUNK + t] = s[t] - c;      // exclusive
    if (t == 255) totals[cloud] = s[255];
}

// ---- Kernel 3: ordered compaction -> normalized point coords (SoA) ---------
__global__ void k_compact(const float* __restrict__ pred, const float* __restrict__ tgt,
                          const int* __restrict__ offsets, float* __restrict__ pts) {
    int cloud = blockIdx.x >> 8;
    int chunk = blockIdx.x & 255;
    int t = threadIdx.x;
    const float* src = cloud_src(pred, tgt, cloud) + chunk * 1024;
    float4 v = reinterpret_cast<const float4*>(src)[t];
    int f0 = v.x > 0.5f, f1 = v.y > 0.5f, f2 = v.z > 0.5f, f3 = v.w > 0.5f;
    int cnt = f0 + f1 + f2 + f3;
    __shared__ int s[256];
    s[t] = cnt; __syncthreads();
    for (int o = 1; o < 256; o <<= 1) {
        int x = (t >= o) ? s[t - o] : 0;
        __syncthreads();
        s[t] += x;
        __syncthreads();
    }
    int rank = offsets[cloud * NCHUNK + chunk] + (s[t] - cnt);  // global rank of this thread's first active
    float* px = pts + (size_t)cloud * 3 * PTS_PAD;
    float* py = px + PTS_PAD;
    float* pz = py + PTS_PAD;
    int eidx = chunk * 1024 + t * 4;
    int flags[4] = {f0, f1, f2, f3};
    #pragma unroll
    for (int e = 0; e < 4; ++e) {
        if (flags[e]) {
            if (rank < MAXPTS) {
                int idx = eidx + e;
                int d = idx >> 12, h = (idx >> 6) & 63, w = idx & 63;
                px[rank] = fmaf((float)d, SCALE, -1.0f);
                py[rank] = fmaf((float)h, SCALE, -1.0f);
                pz[rank] = fmaf((float)w, SCALE, -1.0f);
            }
            rank++;
        }
    }
}

// ---- Kernel 4: chamfer partial mins ----------------------------------------
// grid = NTASK * QB * NSEG = 512 blocks, 256 threads.
// Each thread: NQ=10 queries in regs; refs staged (x,y,z,|r|^2) in LDS.
// Inner tracks min_j (nr_j - 2 q.r_j); nq added (and clamp) in reduce kernel.
__global__ __launch_bounds__(256) void k_chamfer(const float* __restrict__ pts,
                                                 const int* __restrict__ totals,
                                                 float* __restrict__ partial) {
    int task = blockIdx.x >> 6;          // 0..7  (= 2*b + dir)
    int rem  = blockIdx.x & 63;
    int qb   = rem >> 4;                 // 0..3
    int seg  = rem & 15;                 // 0..15
    int b    = task >> 1;
    int dir  = task & 1;
    int qc   = 2 * b + dir;              // query cloud
    int rc   = 2 * b + (dir ^ 1);        // ref cloud
    int tid  = threadIdx.x;

    const float* qx = pts + (size_t)qc * 3 * PTS_PAD;
    const float* qy = qx + PTS_PAD;
    const float* qz = qy + PTS_PAD;
    const float* rx = pts + (size_t)rc * 3 * PTS_PAD;
    const float* ry = rx + PTS_PAD;
    const float* rz = ry + PTS_PAD;
    int countR = min(totals[rc], MAXPTS);

    __shared__ float4 tile[SEGLEN];
    for (int l = tid; l < SEGLEN; l += 256) {
        int j = seg * SEGLEN + l;
        float x = 0.f, y = 0.f, z = 0.f, nr = 1e30f;
        if (j < countR) {
            x = rx[j]; y = ry[j]; z = rz[j];
            nr = fmaf(x, x, fmaf(y, y, z * z));
        }
        tile[l] = make_float4(x, y, z, nr);
    }
    __syncthreads();

    float qxr[NQ], qyr[NQ], qzr[NQ], m[NQ];
    #pragma unroll
    for (int k = 0; k < NQ; ++k) {
        int qi = qb * (NQ * 256) + k * 256 + tid;
        qxr[k] = qx[qi]; qyr[k] = qy[qi]; qzr[k] = qz[qi];
        m[k] = 1e30f;
    }

    #pragma unroll 2
    for (int j = 0; j < SEGLEN; ++j) {
        float4 r = tile[j];
        #pragma unroll
        for (int k = 0; k < NQ; ++k) {
            float t0 = qxr[k] * r.x;
            t0 = fmaf(qyr[k], r.y, t0);
            t0 = fmaf(qzr[k], r.z, t0);
            float s = fmaf(-2.0f, t0, r.w);   // nr - 2 q.r
            m[k] = fminf(m[k], s);
        }
    }

    float* out = partial + ((size_t)task * NSEG + seg) * PTS_PAD;
    #pragma unroll
    for (int k = 0; k < NQ; ++k) {
        int qi = qb * (NQ * 256) + k * 256 + tid;
        out[qi] = m[k];
    }
}

// ---- Kernel 5: min over segments, add nq, clamp, masked block sum ----------
__global__ void k_reduce(const float* __restrict__ pts, const int* __restrict__ totals,
                         const float* __restrict__ partial, float* __restrict__ bsum) {
    int task = blockIdx.x / NRB;
    int rb   = blockIdx.x % NRB;
    int tid  = threadIdx.x;
    int qi   = rb * 256 + tid;
    int qc   = 2 * (task >> 1) + (task & 1);
    int countQ = min(totals[qc], MAXPTS);

    float mn = 1e30f;
    const float* p = partial + (size_t)task * NSEG * PTS_PAD + qi;
    #pragma unroll
    for (int s = 0; s < NSEG; ++s) mn = fminf(mn, p[s * PTS_PAD]);

    float contrib = 0.f;
    if (qi < countQ) {
        const float* qx = pts + (size_t)qc * 3 * PTS_PAD;
        float x = qx[qi], y = qx[PTS_PAD + qi], z = qx[2 * PTS_PAD + qi];
        float nq = fmaf(x, x, fmaf(y, y, z * z));
        contrib = fmaxf(nq + mn, 0.f);
    }
    __shared__ float sb[256];
    sb[tid] = contrib; __syncthreads();
    for (int o = 128; o > 0; o >>= 1) {
        if (tid < o) sb[tid] += sb[tid + o];
        __syncthreads();
    }
    if (tid == 0) bsum[task * NRB + rb] = sb[0];
}

// ---- Kernel 6: deterministic final combine ---------------------------------
__global__ void k_final(const float* __restrict__ bsum, const int* __restrict__ totals,
                        float* __restrict__ out) {
    float total = 0.f, nv = 0.f;
    for (int b = 0; b < 4; ++b) {
        float s1 = 0.f, s2 = 0.f;
        for (int i = 0; i < NRB; ++i) {
            s1 += bsum[(2 * b) * NRB + i];
            s2 += bsum[(2 * b + 1) * NRB + i];
        }
        int c1 = min(totals[2 * b], MAXPTS);
        int c2 = min(totals[2 * b + 1], MAXPTS);
        float cd = s1 / fmaxf((float)c1, 1.f) + s2 / fmaxf((float)c2, 1.f);
        if (c1 > 0 && c2 > 0) { total += cd; nv += 1.f; }
    }
    out[0] = (nv > 0.f) ? total / nv : 0.f;
}

extern "C" void kernel_launch(void* const* d_in, const int* in_sizes, int n_in,
                              void* d_out, int out_size, void* d_ws, size_t ws_size,
                              hipStream_t stream) {
    const float* pred = (const float*)d_in[0];
    const float* tgt  = (const float*)d_in[1];
    float* out = (float*)d_out;

    char* ws = (char*)d_ws;
    int*   totals  = (int*)(ws + WS_TOTALS);
    int*   counts  = (int*)(ws + WS_COUNTS);
    int*   offsets = (int*)(ws + WS_OFFSETS);
    float* pts     = (float*)(ws + WS_PTS);
    float* partial = (float*)(ws + WS_PARTIAL);
    float* bsum    = (float*)(ws + WS_BSUM);

    // zero pts pad region (pad queries read as (0,0,0); masked in reduce)
    hipMemsetAsync(pts, 0, (size_t)NCLOUD * 3 * PTS_PAD * sizeof(float), stream);

    k_count  <<<NCLOUD * NCHUNK, 256, 0, stream>>>(pred, tgt, counts);
    k_scan   <<<NCLOUD,          256, 0, stream>>>(counts, offsets, totals);
    k_compact<<<NCLOUD * NCHUNK, 256, 0, stream>>>(pred, tgt, offsets, pts);
    k_chamfer<<<NTASK * QB * NSEG, 256, 0, stream>>>(pts, totals, partial);
    k_reduce <<<NTASK * NRB,     256, 0, stream>>>(pts, totals, partial, bsum);
    k_final  <<<1, 1, 0, stream>>>(bsum, totals, out);
}

// Round 2
// 90.367 us; speedup vs baseline: 1.1705x; 1.1705x over previous
//
#include <hip/hip_runtime.h>
#include <hip/hip_bf16.h>

// ChamferDistanceLoss via exact-integer f16 MFMA.
// dist_int(q,r) = nq + nr - 2 q.r  computed as K=5 MFMA dot:
//   A = [-2qd, -2qh, -2qw, 8, 1],  B = [rd, rh, rw, nr>>3, nr&7]
// All operands are small integers, exact in f16; products exact in fp32 acc.
// min over refs commutes with +nq; scale by (2/63)^2 at the end.

#define NVOX      262144
#define NCHUNK    256
#define MAXPTS    10000
#define PTS_PAD   10240
#define NCLOUD    8
#define NTASK     8
#define NRB       40         // reduce blocks per task
#define QPB       128        // queries per chamfer block (4 waves x 32)
#define BPT       80         // chamfer blocks per task
#define CH_TILES  128        // j-tiles staged per LDS chunk (2048 refs, 32KB)
#define CHUNKS    5
#define SCALE     (2.0f/63.0f)

typedef _Float16 half8 __attribute__((ext_vector_type(8)));
typedef float    f32x4 __attribute__((ext_vector_type(4)));

// ---------------- workspace layout (bytes) ----------------
#define WS_TOTALS   0           // 8 ints
#define WS_COUNTS   1024        // 8*256 ints
#define WS_OFFSETS  16384       // 8*256 ints
#define WS_AFRAG    32768       // 8*10240*16B
#define WS_BFRAG    1343488     // 8*10240*16B
#define WS_NQ       2654208     // 8*10240 floats
#define WS_SMIN     2981888     // 8*10240 floats
#define WS_BSUM     3309568     // 8*40 floats

__device__ __forceinline__ const float* cloud_src(const float* pred, const float* tgt, int cloud) {
    const float* base = (cloud & 1) ? tgt : pred;
    return base + (size_t)(cloud >> 1) * NVOX;
}

// ---- Kernel 0: init pads ---------------------------------------------------
__global__ void k_init(half8* __restrict__ Afrag, half8* __restrict__ Bfrag,
                       float* __restrict__ nqint) {
    int i = blockIdx.x * 256 + threadIdx.x;   // 0 .. 8*10240-1
    half8 za = {0, 0, 0, 0, 0, 0, 0, 0};
    half8 zb = {0, 0, 0, (_Float16)4096, 0, 0, 0, 0};   // pad ref: s = 8*4096 = 32768
    Afrag[i] = za;
    Bfrag[i] = zb;
    nqint[i] = 0.f;
}

// ---- Kernel 1: per-chunk active counts -------------------------------------
__global__ void k_count(const float* __restrict__ pred, const float* __restrict__ tgt,
                        int* __restrict__ counts) {
    int cloud = blockIdx.x >> 8;
    int chunk = blockIdx.x & 255;
    int t = threadIdx.x;
    const float* src = cloud_src(pred, tgt, cloud) + chunk * 1024;
    float4 v = reinterpret_cast<const float4*>(src)[t];
    int cnt = (v.x > 0.5f) + (v.y > 0.5f) + (v.z > 0.5f) + (v.w > 0.5f);
    __shared__ int s[256];
    s[t] = cnt; __syncthreads();
    for (int o = 128; o > 0; o >>= 1) {
        if (t < o) s[t] += s[t + o];
        __syncthreads();
    }
    if (t == 0) counts[cloud * NCHUNK + chunk] = s[0];
}

// ---- Kernel 2: exclusive scan of chunk counts per cloud --------------------
__global__ void k_scan(const int* __restrict__ counts, int* __restrict__ offsets,
                       int* __restrict__ totals) {
    int cloud = blockIdx.x;
    int t = threadIdx.x;
    int c = counts[cloud * NCHUNK + t];
    __shared__ int s[256];
    s[t] = c; __syncthreads();
    for (int o = 1; o < 256; o <<= 1) {
        int v = (t >= o) ? s[t - o] : 0;
        __syncthreads();
        s[t] += v;
        __syncthreads();
    }
    offsets[cloud * NCHUNK + t] = s[t] - c;
    if (t == 255) totals[cloud] = s[255];
}

// ---- Kernel 3: ordered compaction -> A/B fragments + nq --------------------
__global__ void k_compact(const float* __restrict__ pred, const float* __restrict__ tgt,
                          const int* __restrict__ offsets,
                          half8* __restrict__ Afrag, half8* __restrict__ Bfrag,
                          float* __restrict__ nqint) {
    int cloud = blockIdx.x >> 8;
    int chunk = blockIdx.x & 255;
    int t = threadIdx.x;
    const float* src = cloud_src(pred, tgt, cloud) + chunk * 1024;
    float4 v = reinterpret_cast<const float4*>(src)[t];
    int f0 = v.x > 0.5f, f1 = v.y > 0.5f, f2 = v.z > 0.5f, f3 = v.w > 0.5f;
    int cnt = f0 + f1 + f2 + f3;
    __shared__ int s[256];
    s[t] = cnt; __syncthreads();
    for (int o = 1; o < 256; o <<= 1) {
        int x = (t >= o) ? s[t - o] : 0;
        __syncthreads();
        s[t] += x;
        __syncthreads();
    }
    int rank = offsets[cloud * NCHUNK + chunk] + (s[t] - cnt);
    int eidx = chunk * 1024 + t * 4;
    int flags[4] = {f0, f1, f2, f3};
    size_t base = (size_t)cloud * PTS_PAD;
    #pragma unroll
    for (int e = 0; e < 4; ++e) {
        if (flags[e]) {
            if (rank < MAXPTS) {
                int idx = eidx + e;
                int d = idx >> 12, h = (idx >> 6) & 63, w = idx & 63;
                int nr = d * d + h * h + w * w;
                half8 A = {(_Float16)(-2 * d), (_Float16)(-2 * h), (_Float16)(-2 * w),
                           (_Float16)8, (_Float16)1, 0, 0, 0};
                half8 B = {(_Float16)d, (_Float16)h, (_Float16)w,
                           (_Float16)(nr >> 3), (_Float16)(nr & 7), 0, 0, 0};
                Afrag[base + rank] = A;
                Bfrag[base + rank] = B;
                nqint[base + rank] = (float)nr;
            }
            rank++;
        }
    }
}

// ---- Kernel 4: chamfer min via MFMA ----------------------------------------
// grid = NTASK*BPT = 640 blocks, 256 thr (4 waves). Wave owns 32 queries
// (2 A-frag i-tiles), iterates all 10240 refs in LDS-staged chunks.
__global__ __launch_bounds__(256) void k_chamfer(const half8* __restrict__ Afrag,
                                                 const half8* __restrict__ Bfrag,
                                                 float* __restrict__ smin) {
    int task = blockIdx.x / BPT;
    int qblk = blockIdx.x % BPT;
    int b = task >> 1, dir = task & 1;
    int qc = 2 * b + dir;
    int rc = 2 * b + (dir ^ 1);
    int tid = threadIdx.x, wave = tid >> 6, lane = tid & 63;

    __shared__ f32x4 ldsv[CH_TILES * 16 + 1];   // 32KB frags + 16B zero slot
    char* lds = (char*)ldsv;
    if (tid == 0) { f32x4 z = {0, 0, 0, 0}; ldsv[CH_TILES * 16] = z; }

    int qbase = qblk * QPB + wave * 32;
    half8 a0 = {0, 0, 0, 0, 0, 0, 0, 0};
    half8 a1 = a0;
    if (lane < 16) {
        a0 = Afrag[(size_t)qc * PTS_PAD + qbase + lane];
        a1 = Afrag[(size_t)qc * PTS_PAD + qbase + 16 + lane];
    }
    f32x4 m0 = {1e30f, 1e30f, 1e30f, 1e30f};
    f32x4 m1 = m0;

    const float4* Bsrc = (const float4*)(Bfrag + (size_t)rc * PTS_PAD);
    const char* rdbase = lds + ((lane < 16) ? lane * 16 : CH_TILES * 256);

    for (int c = 0; c < CHUNKS; ++c) {
        __syncthreads();
        const float4* src = Bsrc + c * (CH_TILES * 16);
        float4* dst = (float4*)lds;
        #pragma unroll
        for (int i = 0; i < 8; ++i) dst[tid + i * 256] = src[tid + i * 256];
        __syncthreads();
        #pragma unroll 8
        for (int t = 0; t < CH_TILES; ++t) {
            half8 bf = *(const half8*)(rdbase + t * 256);
            f32x4 zero = {0, 0, 0, 0};
            f32x4 d0 = __builtin_amdgcn_mfma_f32_16x16x32_f16(a0, bf, zero, 0, 0, 0);
            f32x4 d1 = __builtin_amdgcn_mfma_f32_16x16x32_f16(a1, bf, zero, 0, 0, 0);
            #pragma unroll
            for (int e = 0; e < 4; ++e) {
                m0[e] = fminf(m0[e], d0[e]);
                m1[e] = fminf(m1[e], d1[e]);
            }
        }
    }

    // min across the 16 cols: reduce over lanes within each 16-lane group
    #pragma unroll
    for (int e = 0; e < 4; ++e) {
        float v0 = m0[e], v1 = m1[e];
        #pragma unroll
        for (int o = 1; o < 16; o <<= 1) {
            v0 = fminf(v0, __shfl_xor(v0, o));
            v1 = fminf(v1, __shfl_xor(v1, o));
        }
        m0[e] = v0; m1[e] = v1;
    }
    if ((lane & 15) == 0) {
        int rowgrp = (lane >> 4) * 4;   // D row = (lane>>4)*4 + e
        float* out = smin + (size_t)task * PTS_PAD + qbase;
        #pragma unroll
        for (int e = 0; e < 4; ++e) {
            out[rowgrp + e] = m0[e];
            out[16 + rowgrp + e] = m1[e];
        }
    }
}

// ---- Kernel 5: add nq, scale, clamp, masked block sum ----------------------
__global__ void k_reduce(const float* __restrict__ nqint, const int* __restrict__ totals,
                         const float* __restrict__ smin, float* __restrict__ bsum) {
    int task = blockIdx.x / NRB;
    int rb   = blockIdx.x % NRB;
    int tid  = threadIdx.x;
    int qi   = rb * 256 + tid;
    int qc   = 2 * (task >> 1) + (task & 1);
    int countQ = min(totals[qc], MAXPTS);

    const float SC2 = SCALE * SCALE;
    float contrib = 0.f;
    if (qi < countQ) {
        float m = smin[(size_t)task * PTS_PAD + qi];
        float nq = nqint[(size_t)qc * PTS_PAD + qi];
        contrib = fmaxf((nq + m) * SC2, 0.f);
    }
    __shared__ float sb[256];
    sb[tid] = contrib; __syncthreads();
    for (int o = 128; o > 0; o >>= 1) {
        if (tid < o) sb[tid] += sb[tid + o];
        __syncthreads();
    }
    if (tid == 0) bsum[task * NRB + rb] = sb[0];
}

// ---- Kernel 6: deterministic final combine ---------------------------------
__global__ void k_final(const float* __restrict__ bsum, const int* __restrict__ totals,
                        float* __restrict__ out) {
    float total = 0.f, nv = 0.f;
    for (int b = 0; b < 4; ++b) {
        float s1 = 0.f, s2 = 0.f;
        for (int i = 0; i < NRB; ++i) {
            s1 += bsum[(2 * b) * NRB + i];
            s2 += bsum[(2 * b + 1) * NRB + i];
        }
        int c1 = min(totals[2 * b], MAXPTS);
        int c2 = min(totals[2 * b + 1], MAXPTS);
        float cd = s1 / fmaxf((float)c1, 1.f) + s2 / fmaxf((float)c2, 1.f);
        if (c1 > 0 && c2 > 0) { total += cd; nv += 1.f; }
    }
    out[0] = (nv > 0.f) ? total / nv : 0.f;
}

extern "C" void kernel_launch(void* const* d_in, const int* in_sizes, int n_in,
                              void* d_out, int out_size, void* d_ws, size_t ws_size,
                              hipStream_t stream) {
    const float* pred = (const float*)d_in[0];
    const float* tgt  = (const float*)d_in[1];
    float* out = (float*)d_out;

    char* ws = (char*)d_ws;
    int*   totals  = (int*)(ws + WS_TOTALS);
    int*   counts  = (int*)(ws + WS_COUNTS);
    int*   offsets = (int*)(ws + WS_OFFSETS);
    half8* Afrag   = (half8*)(ws + WS_AFRAG);
    half8* Bfrag   = (half8*)(ws + WS_BFRAG);
    float* nqint   = (float*)(ws + WS_NQ);
    float* smin    = (float*)(ws + WS_SMIN);
    float* bsum    = (float*)(ws + WS_BSUM);

    k_init   <<<NCLOUD * PTS_PAD / 256, 256, 0, stream>>>(Afrag, Bfrag, nqint);
    k_count  <<<NCLOUD * NCHUNK, 256, 0, stream>>>(pred, tgt, counts);
    k_scan   <<<NCLOUD,          256, 0, stream>>>(counts, offsets, totals);
    k_compact<<<NCLOUD * NCHUNK, 256, 0, stream>>>(pred, tgt, offsets, Afrag, Bfrag, nqint);
    k_chamfer<<<NTASK * BPT,     256, 0, stream>>>(Afrag, Bfrag, smin);
    k_reduce <<<NTASK * NRB,     256, 0, stream>>>(nqint, totals, smin, bsum);
    k_final  <<<1, 1, 0, stream>>>(bsum, totals, out);
}

// Round 3
// 72.375 us; speedup vs baseline: 1.4615x; 1.2486x over previous
//
#include <hip/hip_runtime.h>
#include <hip/hip_bf16.h>

// ChamferDistanceLoss via exact-integer f16 MFMA (32x32x16).
// dist_int(q,r) = nq + nr - 2 q.r  computed as K=5 dot inside K=16 MFMA:
//   A = [-2qd, -2qh, -2qw, 8, 1, 0...],  B = [rd, rh, rw, nr>>3, nr&7, garbage-ok...]
// All operands small integers, exact in f16; products exact in fp32 acc.
// min over refs commutes with +nq; scale by (2/63)^2 at the end.

#define NVOX      262144
#define NCHUNK    256
#define MAXPTS    10000
#define PTS_PAD   10240
#define NCLOUD    8
#define NTASK     8
#define NRB       40         // reduce blocks per task
#define QPB       256        // queries per chamfer block (4 waves x 64)
#define NQB       40         // query blocks per task
#define RSPLIT    2          // ref splits per task
#define RLEN      5120       // refs per split
#define CH_REFS   1024       // refs staged per LDS chunk (16 KB)
#define CH_ITERS  16         // j-tile pairs per chunk (64 refs each)
#define NCH       5          // chunks per split
#define SCALE     (2.0f/63.0f)

typedef _Float16 half8  __attribute__((ext_vector_type(8)));
typedef float    f32x16 __attribute__((ext_vector_type(16)));

// ---------------- workspace layout (bytes) ----------------
#define WS_TOTALS   0           // 8 ints
#define WS_COUNTS   1024        // 8*256 ints
#define WS_OFFSETS  16384       // 8*256 ints
#define WS_AFRAG    32768       // 8*10240*16B = 1310720
#define WS_BFRAG    1343488     // 8*10240*16B = 1310720
#define WS_NQ       2654208     // 8*10240 f32 = 327680
#define WS_SMIN     2981888     // 8*2*10240 f32 = 655360
#define WS_BSUM     3637248     // 8*40 f32

__device__ __forceinline__ const float* cloud_src(const float* pred, const float* tgt, int cloud) {
    const float* base = (cloud & 1) ? tgt : pred;
    return base + (size_t)(cloud >> 1) * NVOX;
}

// ---- Kernel 0: init pads ---------------------------------------------------
__global__ void k_init(half8* __restrict__ Afrag, half8* __restrict__ Bfrag,
                       float* __restrict__ nqint) {
    int i = blockIdx.x * 256 + threadIdx.x;   // 0 .. 8*10240-1
    half8 za = {0, 0, 0, 0, 0, 0, 0, 0};
    half8 zb = {0, 0, 0, (_Float16)4096, 0, 0, 0, 0};   // pad ref: s = 8*4096 = 32768 > any real s
    Afrag[i] = za;
    Bfrag[i] = zb;
    nqint[i] = 0.f;
}

// ---- Kernel 1: per-chunk active counts -------------------------------------
__global__ void k_count(const float* __restrict__ pred, const float* __restrict__ tgt,
                        int* __restrict__ counts) {
    int cloud = blockIdx.x >> 8;
    int chunk = blockIdx.x & 255;
    int t = threadIdx.x;
    const float* src = cloud_src(pred, tgt, cloud) + chunk * 1024;
    float4 v = reinterpret_cast<const float4*>(src)[t];
    int cnt = (v.x > 0.5f) + (v.y > 0.5f) + (v.z > 0.5f) + (v.w > 0.5f);
    __shared__ int s[256];
    s[t] = cnt; __syncthreads();
    for (int o = 128; o > 0; o >>= 1) {
        if (t < o) s[t] += s[t + o];
        __syncthreads();
    }
    if (t == 0) counts[cloud * NCHUNK + chunk] = s[0];
}

// ---- Kernel 2: exclusive scan of chunk counts per cloud --------------------
__global__ void k_scan(const int* __restrict__ counts, int* __restrict__ offsets,
                       int* __restrict__ totals) {
    int cloud = blockIdx.x;
    int t = threadIdx.x;
    int c = counts[cloud * NCHUNK + t];
    __shared__ int s[256];
    s[t] = c; __syncthreads();
    for (int o = 1; o < 256; o <<= 1) {
        int v = (t >= o) ? s[t - o] : 0;
        __syncthreads();
        s[t] += v;
        __syncthreads();
    }
    offsets[cloud * NCHUNK + t] = s[t] - c;
    if (t == 255) totals[cloud] = s[255];
}

// ---- Kernel 3: ordered compaction -> A/B fragments + nq --------------------
__global__ void k_compact(const float* __restrict__ pred, const float* __restrict__ tgt,
                          const int* __restrict__ offsets,
                          half8* __restrict__ Afrag, half8* __restrict__ Bfrag,
                          float* __restrict__ nqint) {
    int cloud = blockIdx.x >> 8;
    int chunk = blockIdx.x & 255;
    int t = threadIdx.x;
    const float* src = cloud_src(pred, tgt, cloud) + chunk * 1024;
    float4 v = reinterpret_cast<const float4*>(src)[t];
    int f0 = v.x > 0.5f, f1 = v.y > 0.5f, f2 = v.z > 0.5f, f3 = v.w > 0.5f;
    int cnt = f0 + f1 + f2 + f3;
    __shared__ int s[256];
    s[t] = cnt; __syncthreads();
    for (int o = 1; o < 256; o <<= 1) {
        int x = (t >= o) ? s[t - o] : 0;
        __syncthreads();
        s[t] += x;
        __syncthreads();
    }
    int rank = offsets[cloud * NCHUNK + chunk] + (s[t] - cnt);
    int eidx = chunk * 1024 + t * 4;
    int flags[4] = {f0, f1, f2, f3};
    size_t base = (size_t)cloud * PTS_PAD;
    #pragma unroll
    for (int e = 0; e < 4; ++e) {
        if (flags[e]) {
            if (rank < MAXPTS) {
                int idx = eidx + e;
                int d = idx >> 12, h = (idx >> 6) & 63, w = idx & 63;
                int nr = d * d + h * h + w * w;
                half8 A = {(_Float16)(-2 * d), (_Float16)(-2 * h), (_Float16)(-2 * w),
                           (_Float16)8, (_Float16)1, 0, 0, 0};
                half8 B = {(_Float16)d, (_Float16)h, (_Float16)w,
                           (_Float16)(nr >> 3), (_Float16)(nr & 7), 0, 0, 0};
                Afrag[base + rank] = A;
                Bfrag[base + rank] = B;
                nqint[base + rank] = (float)nr;
            }
            rank++;
        }
    }
}

// ---- Kernel 4: chamfer min via 32x32x16 MFMA -------------------------------
// grid = NTASK*NQB*RSPLIT = 640 blocks, 256 thr (4 waves). Wave owns 64
// queries (2 A i-tiles); block scans RLEN refs LDS-staged in 16KB chunks.
// Inner step: 2 ds_read_b128 + 4 MFMA + 32 min3 (covers 64q x 64r).
__global__ __launch_bounds__(256) void k_chamfer(const half8* __restrict__ Afrag,
                                                 const half8* __restrict__ Bfrag,
                                                 float* __restrict__ smin) {
    int task = blockIdx.x / (NQB * RSPLIT);
    int rem  = blockIdx.x % (NQB * RSPLIT);
    int qb   = rem / RSPLIT;
    int rs   = rem % RSPLIT;
    int b = task >> 1, dir = task & 1;
    int qc = 2 * b + dir;
    int rc = 2 * b + (dir ^ 1);
    int tid = threadIdx.x, wave = tid >> 6, lane = tid & 63;

    __shared__ float4 ldsv[CH_REFS];   // 16 KB
    char* lds = (char*)ldsv;

    int qbase = qb * QPB + wave * 64;
    half8 zero8 = {0, 0, 0, 0, 0, 0, 0, 0};
    half8 a0 = zero8, a1 = zero8;
    if (lane < 32) {
        a0 = Afrag[(size_t)qc * PTS_PAD + qbase + (lane & 31)];
        a1 = Afrag[(size_t)qc * PTS_PAD + qbase + 32 + (lane & 31)];
    }
    f32x16 m0, m1;
    #pragma unroll
    for (int e = 0; e < 16; ++e) { m0[e] = 1e30f; m1[e] = 1e30f; }
    f32x16 cz;
    #pragma unroll
    for (int e = 0; e < 16; ++e) cz[e] = 0.f;

    const float4* Bsrc = (const float4*)(Bfrag + (size_t)rc * PTS_PAD + rs * RLEN);
    const char* rdbase = lds + (lane & 31) * 16;   // lanes>=32: A is zero there, B garbage ok

    for (int c = 0; c < NCH; ++c) {
        __syncthreads();
        const float4* src = Bsrc + c * CH_REFS;
        #pragma unroll
        for (int i = 0; i < 4; ++i) ldsv[tid + i * 256] = src[tid + i * 256];
        __syncthreads();
        #pragma unroll 4
        for (int t = 0; t < CH_ITERS; ++t) {
            half8 b0 = *(const half8*)(rdbase + t * 1024);
            half8 b1 = *(const half8*)(rdbase + t * 1024 + 512);
            f32x16 d00 = __builtin_amdgcn_mfma_f32_32x32x16_f16(a0, b0, cz, 0, 0, 0);
            f32x16 d01 = __builtin_amdgcn_mfma_f32_32x32x16_f16(a0, b1, cz, 0, 0, 0);
            f32x16 d10 = __builtin_amdgcn_mfma_f32_32x32x16_f16(a1, b0, cz, 0, 0, 0);
            f32x16 d11 = __builtin_amdgcn_mfma_f32_32x32x16_f16(a1, b1, cz, 0, 0, 0);
            #pragma unroll
            for (int e = 0; e < 16; ++e) {
                m0[e] = fminf(fminf(m0[e], d00[e]), d01[e]);   // -> v_min3_f32
                m1[e] = fminf(fminf(m1[e], d10[e]), d11[e]);
            }
        }
    }

    // min across 32 cols (refs): reduce over the 32-lane half-groups
    #pragma unroll
    for (int e = 0; e < 16; ++e) {
        float v0 = m0[e], v1 = m1[e];
        #pragma unroll
        for (int o = 1; o < 32; o <<= 1) {
            v0 = fminf(v0, __shfl_xor(v0, o));
            v1 = fminf(v1, __shfl_xor(v1, o));
        }
        m0[e] = v0; m1[e] = v1;
    }
    if ((lane & 31) == 0) {
        int half = lane >> 5;   // D row = (e&3) + 8*(e>>2) + 4*half
        float* out = smin + ((size_t)task * RSPLIT + rs) * PTS_PAD + qbase;
        #pragma unroll
        for (int e = 0; e < 16; ++e) {
            int row = (e & 3) + 8 * (e >> 2) + 4 * half;
            out[row] = m0[e];
            out[32 + row] = m1[e];
        }
    }
}

// ---- Kernel 5: min over splits, add nq, scale, clamp, masked block sum -----
__global__ void k_reduce(const float* __restrict__ nqint, const int* __restrict__ totals,
                         const float* __restrict__ smin, float* __restrict__ bsum) {
    int task = blockIdx.x / NRB;
    int rb   = blockIdx.x % NRB;
    int tid  = threadIdx.x;
    int qi   = rb * 256 + tid;
    int qc   = 2 * (task >> 1) + (task & 1);
    int countQ = min(totals[qc], MAXPTS);

    const float SC2 = SCALE * SCALE;
    float contrib = 0.f;
    if (qi < countQ) {
        float m = fminf(smin[((size_t)task * RSPLIT + 0) * PTS_PAD + qi],
                        smin[((size_t)task * RSPLIT + 1) * PTS_PAD + qi]);
        float nq = nqint[(size_t)qc * PTS_PAD + qi];
        contrib = fmaxf((nq + m) * SC2, 0.f);
    }
    __shared__ float sb[256];
    sb[tid] = contrib; __syncthreads();
    for (int o = 128; o > 0; o >>= 1) {
        if (tid < o) sb[tid] += sb[tid + o];
        __syncthreads();
    }
    if (tid == 0) bsum[task * NRB + rb] = sb[0];
}

// ---- Kernel 6: deterministic final combine ---------------------------------
__global__ void k_final(const float* __restrict__ bsum, const int* __restrict__ totals,
                        float* __restrict__ out) {
    float total = 0.f, nv = 0.f;
    for (int b = 0; b < 4; ++b) {
        float s1 = 0.f, s2 = 0.f;
        for (int i = 0; i < NRB; ++i) {
            s1 += bsum[(2 * b) * NRB + i];
            s2 += bsum[(2 * b + 1) * NRB + i];
        }
        int c1 = min(totals[2 * b], MAXPTS);
        int c2 = min(totals[2 * b + 1], MAXPTS);
        float cd = s1 / fmaxf((float)c1, 1.f) + s2 / fmaxf((float)c2, 1.f);
        if (c1 > 0 && c2 > 0) { total += cd; nv += 1.f; }
    }
    out[0] = (nv > 0.f) ? total / nv : 0.f;
}

extern "C" void kernel_launch(void* const* d_in, const int* in_sizes, int n_in,
                              void* d_out, int out_size, void* d_ws, size_t ws_size,
                              hipStream_t stream) {
    const float* pred = (const float*)d_in[0];
    const float* tgt  = (const float*)d_in[1];
    float* out = (float*)d_out;

    char* ws = (char*)d_ws;
    int*   totals  = (int*)(ws + WS_TOTALS);
    int*   counts  = (int*)(ws + WS_COUNTS);
    int*   offsets = (int*)(ws + WS_OFFSETS);
    half8* Afrag   = (half8*)(ws + WS_AFRAG);
    half8* Bfrag   = (half8*)(ws + WS_BFRAG);
    float* nqint   = (float*)(ws + WS_NQ);
    float* smin    = (float*)(ws + WS_SMIN);
    float* bsum    = (float*)(ws + WS_BSUM);

    k_init   <<<NCLOUD * PTS_PAD / 256, 256, 0, stream>>>(Afrag, Bfrag, nqint);
    k_count  <<<NCLOUD * NCHUNK, 256, 0, stream>>>(pred, tgt, counts);
    k_scan   <<<NCLOUD,          256, 0, stream>>>(counts, offsets, totals);
    k_compact<<<NCLOUD * NCHUNK, 256, 0, stream>>>(pred, tgt, offsets, Afrag, Bfrag, nqint);
    k_chamfer<<<NTASK * NQB * RSPLIT, 256, 0, stream>>>(Afrag, Bfrag, smin);
    k_reduce <<<NTASK * NRB,     256, 0, stream>>>(nqint, totals, smin, bsum);
    k_final  <<<1, 1, 0, stream>>>(bsum, totals, out);
}

// Round 4
// 51.416 us; speedup vs baseline: 2.0572x; 1.4076x over previous
//
#include <hip/hip_runtime.h>
#include <hip/hip_bf16.h>

// ChamferDistanceLoss via exact-integer f16 MFMA (32x32x16), operand-swapped:
//   A (rows, LDS-streamed)  = refs   enc [rd, rh, rw, nr>>3, nr&7, 0,0,0]
//   B (cols, register-held) = queries enc [-2qd, -2qh, -2qw, 8, 1, 0,0,0]
// s = nr - 2 q.r exact (f16 inputs exact ints, fp32 products/sums exact).
// Each lane's D col = one query -> per-lane scalar min accumulator.
// min commutes with +nq; scale by (2/63)^2 at the end.

#define NVOX      262144
#define NCHUNK    256
#define MAXPTS    10000
#define PTS_PAD   10240
#define NCLOUD    8
#define NTASK     8
#define NRB       40         // reduce blocks per task
#define QPB       256        // queries per chamfer block (4 waves x 64)
#define NQB       40         // query blocks per task
#define RSPLIT    4          // ref splits per task
#define RLEN      2560       // refs per split
#define CH_REFS   1280       // refs staged per LDS chunk (20 KB)
#define CH_STEPS  20         // 64-ref steps per chunk
#define NCH       2          // chunks per split
#define SCALE     (2.0f/63.0f)

typedef _Float16 half8  __attribute__((ext_vector_type(8)));
typedef float    f32x16 __attribute__((ext_vector_type(16)));

// ---------------- workspace layout (bytes) ----------------
#define WS_TOTALS   0           // 8 ints
#define WS_COUNTS   1024        // 8*256 ints
#define WS_OFFSETS  16384       // 8*256 ints
#define WS_QFRAG    32768       // 8*10240*16B = 1310720
#define WS_RFRAG    1343488     // 8*10240*16B = 1310720
#define WS_NQ       2654208     // 8*10240 f32 = 327680
#define WS_SMIN     2981888     // 8*4*10240 f32 = 1310720
#define WS_BSUM     4292608     // 8*40 f32

__device__ __forceinline__ const float* cloud_src(const float* pred, const float* tgt, int cloud) {
    const float* base = (cloud & 1) ? tgt : pred;
    return base + (size_t)(cloud >> 1) * NVOX;
}

// ---- Kernel 0: init pads ---------------------------------------------------
__global__ void k_init(half8* __restrict__ Qfrag, half8* __restrict__ Rfrag,
                       float* __restrict__ nqint) {
    int i = blockIdx.x * 256 + threadIdx.x;   // 0 .. 8*10240-1
    half8 zq = {0, 0, 0, 0, 0, 0, 0, 0};                 // pad query: s = 0 (masked later)
    half8 zr = {0, 0, 0, (_Float16)4096, 0, 0, 0, 0};    // pad ref: s = 8*4096 = 32768 > any real
    Qfrag[i] = zq;
    Rfrag[i] = zr;
    nqint[i] = 0.f;
}

// ---- Kernel 1: per-chunk active counts -------------------------------------
__global__ void k_count(const float* __restrict__ pred, const float* __restrict__ tgt,
                        int* __restrict__ counts) {
    int cloud = blockIdx.x >> 8;
    int chunk = blockIdx.x & 255;
    int t = threadIdx.x;
    const float* src = cloud_src(pred, tgt, cloud) + chunk * 1024;
    float4 v = reinterpret_cast<const float4*>(src)[t];
    int cnt = (v.x > 0.5f) + (v.y > 0.5f) + (v.z > 0.5f) + (v.w > 0.5f);
    __shared__ int s[256];
    s[t] = cnt; __syncthreads();
    for (int o = 128; o > 0; o >>= 1) {
        if (t < o) s[t] += s[t + o];
        __syncthreads();
    }
    if (t == 0) counts[cloud * NCHUNK + chunk] = s[0];
}

// ---- Kernel 2: exclusive scan of chunk counts per cloud --------------------
__global__ void k_scan(const int* __restrict__ counts, int* __restrict__ offsets,
                       int* __restrict__ totals) {
    int cloud = blockIdx.x;
    int t = threadIdx.x;
    int c = counts[cloud * NCHUNK + t];
    __shared__ int s[256];
    s[t] = c; __syncthreads();
    for (int o = 1; o < 256; o <<= 1) {
        int v = (t >= o) ? s[t - o] : 0;
        __syncthreads();
        s[t] += v;
        __syncthreads();
    }
    offsets[cloud * NCHUNK + t] = s[t] - c;
    if (t == 255) totals[cloud] = s[255];
}

// ---- Kernel 3: ordered compaction -> Q/R fragments + nq --------------------
__global__ void k_compact(const float* __restrict__ pred, const float* __restrict__ tgt,
                          const int* __restrict__ offsets,
                          half8* __restrict__ Qfrag, half8* __restrict__ Rfrag,
                          float* __restrict__ nqint) {
    int cloud = blockIdx.x >> 8;
    int chunk = blockIdx.x & 255;
    int t = threadIdx.x;
    const float* src = cloud_src(pred, tgt, cloud) + chunk * 1024;
    float4 v = reinterpret_cast<const float4*>(src)[t];
    int f0 = v.x > 0.5f, f1 = v.y > 0.5f, f2 = v.z > 0.5f, f3 = v.w > 0.5f;
    int cnt = f0 + f1 + f2 + f3;
    __shared__ int s[256];
    s[t] = cnt; __syncthreads();
    for (int o = 1; o < 256; o <<= 1) {
        int x = (t >= o) ? s[t - o] : 0;
        __syncthreads();
        s[t] += x;
        __syncthreads();
    }
    int rank = offsets[cloud * NCHUNK + chunk] + (s[t] - cnt);
    int eidx = chunk * 1024 + t * 4;
    int flags[4] = {f0, f1, f2, f3};
    size_t base = (size_t)cloud * PTS_PAD;
    #pragma unroll
    for (int e = 0; e < 4; ++e) {
        if (flags[e]) {
            if (rank < MAXPTS) {
                int idx = eidx + e;
                int d = idx >> 12, h = (idx >> 6) & 63, w = idx & 63;
                int nr = d * d + h * h + w * w;
                half8 Q = {(_Float16)(-2 * d), (_Float16)(-2 * h), (_Float16)(-2 * w),
                           (_Float16)8, (_Float16)1, 0, 0, 0};
                half8 R = {(_Float16)d, (_Float16)h, (_Float16)w,
                           (_Float16)(nr >> 3), (_Float16)(nr & 7), 0, 0, 0};
                Qfrag[base + rank] = Q;
                Rfrag[base + rank] = R;
                nqint[base + rank] = (float)nr;
            }
            rank++;
        }
    }
}

// ---- min-reduce 32 MFMA outputs + carry into a scalar (min3-friendly) ------
__device__ __forceinline__ float mintree(f32x16 d0, f32x16 d1, float m) {
    float t[4];
    #pragma unroll
    for (int e = 0; e < 4; ++e) {
        float u = fminf(fminf(d0[e], d0[e + 4]), d0[e + 8]);
        u = fminf(fminf(u, d0[e + 12]), d1[e]);
        u = fminf(fminf(u, d1[e + 4]), d1[e + 8]);
        u = fminf(u, d1[e + 12]);
        t[e] = u;
    }
    return fminf(fminf(m, fminf(t[0], t[1])), fminf(t[2], t[3]));
}

// ---- Kernel 4: chamfer min via 32x32x16 MFMA, refs-as-rows ------------------
// grid = NTASK*NQB*RSPLIT = 1280 blocks, 256 thr (4 waves). Wave holds 64
// queries (2 B col-tiles); streams RLEN refs as A row-tiles from LDS chunks.
// Per step: 2 ds_read_b128 + 4 MFMA + ~38 min3/min (covers 64q x 64r).
__global__ __launch_bounds__(256, 3) void k_chamfer(const half8* __restrict__ Qfrag,
                                                    const half8* __restrict__ Rfrag,
                                                    float* __restrict__ smin) {
    int task = blockIdx.x / (NQB * RSPLIT);
    int rem  = blockIdx.x % (NQB * RSPLIT);
    int qb   = rem / RSPLIT;
    int rs   = rem % RSPLIT;
    int b = task >> 1, dir = task & 1;
    int qc = 2 * b + dir;
    int rc = 2 * b + (dir ^ 1);
    int tid = threadIdx.x, wave = tid >> 6, lane = tid & 63;

    __shared__ float4 ldsv[CH_REFS];   // 20 KB
    char* lds = (char*)ldsv;

    int qbase = qb * QPB + wave * 64;
    half8 zero8 = {0, 0, 0, 0, 0, 0, 0, 0};
    half8 bq0 = zero8, bq1 = zero8;
    if (lane < 32) {   // lanes>=32 supply k=8..15: must be zero to nullify aliased A reads
        bq0 = Qfrag[(size_t)qc * PTS_PAD + qbase + lane];
        bq1 = Qfrag[(size_t)qc * PTS_PAD + qbase + 32 + lane];
    }
    float m0 = 1e30f, m1 = 1e30f;
    f32x16 cz;
    #pragma unroll
    for (int e = 0; e < 16; ++e) cz[e] = 0.f;

    const float4* Rsrc = (const float4*)(Rfrag + (size_t)rc * PTS_PAD + rs * RLEN);
    const char* rdbase = lds + (lane & 31) * 16;   // lanes>=32 alias lanes<32: B zeros nullify

    for (int c = 0; c < NCH; ++c) {
        __syncthreads();
        const float4* src = Rsrc + c * CH_REFS;
        #pragma unroll
        for (int i = 0; i < CH_REFS / 256; ++i) ldsv[tid + i * 256] = src[tid + i * 256];
        __syncthreads();
        #pragma unroll 2
        for (int t = 0; t < CH_STEPS; ++t) {
            half8 a0 = *(const half8*)(rdbase + t * 1024);
            half8 a1 = *(const half8*)(rdbase + t * 1024 + 512);
            f32x16 d0 = __builtin_amdgcn_mfma_f32_32x32x16_f16(a0, bq0, cz, 0, 0, 0);
            f32x16 d1 = __builtin_amdgcn_mfma_f32_32x32x16_f16(a1, bq0, cz, 0, 0, 0);
            f32x16 d2 = __builtin_amdgcn_mfma_f32_32x32x16_f16(a0, bq1, cz, 0, 0, 0);
            f32x16 d3 = __builtin_amdgcn_mfma_f32_32x32x16_f16(a1, bq1, cz, 0, 0, 0);
            m0 = mintree(d0, d1, m0);
            m1 = mintree(d2, d3, m1);
        }
    }

    // lane L and L+32 hold complementary ref-rows of query col (lane&31)
    m0 = fminf(m0, __shfl_xor(m0, 32));
    m1 = fminf(m1, __shfl_xor(m1, 32));
    if (lane < 32) {
        float* outp = smin + ((size_t)task * RSPLIT + rs) * PTS_PAD + qbase;
        outp[lane] = m0;
        outp[32 + lane] = m1;
    }
}

// ---- Kernel 5: min over splits, add nq, scale, clamp, masked block sum -----
__global__ void k_reduce(const float* __restrict__ nqint, const int* __restrict__ totals,
                         const float* __restrict__ smin, float* __restrict__ bsum) {
    int task = blockIdx.x / NRB;
    int rb   = blockIdx.x % NRB;
    int tid  = threadIdx.x;
    int qi   = rb * 256 + tid;
    int qc   = 2 * (task >> 1) + (task & 1);
    int countQ = min(totals[qc], MAXPTS);

    const float SC2 = SCALE * SCALE;
    float contrib = 0.f;
    if (qi < countQ) {
        const float* s = smin + (size_t)task * RSPLIT * PTS_PAD + qi;
        float m = fminf(fminf(s[0], s[PTS_PAD]), fminf(s[2 * PTS_PAD], s[3 * PTS_PAD]));
        float nq = nqint[(size_t)qc * PTS_PAD + qi];
        contrib = fmaxf((nq + m) * SC2, 0.f);
    }
    __shared__ float sb[256];
    sb[tid] = contrib; __syncthreads();
    for (int o = 128; o > 0; o >>= 1) {
        if (tid < o) sb[tid] += sb[tid + o];
        __syncthreads();
    }
    if (tid == 0) bsum[task * NRB + rb] = sb[0];
}

// ---- Kernel 6: deterministic final combine ---------------------------------
__global__ void k_final(const float* __restrict__ bsum, const int* __restrict__ totals,
                        float* __restrict__ out) {
    float total = 0.f, nv = 0.f;
    for (int b = 0; b < 4; ++b) {
        float s1 = 0.f, s2 = 0.f;
        for (int i = 0; i < NRB; ++i) {
            s1 += bsum[(2 * b) * NRB + i];
            s2 += bsum[(2 * b + 1) * NRB + i];
        }
        int c1 = min(totals[2 * b], MAXPTS);
        int c2 = min(totals[2 * b + 1], MAXPTS);
        float cd = s1 / fmaxf((float)c1, 1.f) + s2 / fmaxf((float)c2, 1.f);
        if (c1 > 0 && c2 > 0) { total += cd; nv += 1.f; }
    }
    out[0] = (nv > 0.f) ? total / nv : 0.f;
}

extern "C" void kernel_launch(void* const* d_in, const int* in_sizes, int n_in,
                              void* d_out, int out_size, void* d_ws, size_t ws_size,
                              hipStream_t stream) {
    const float* pred = (const float*)d_in[0];
    const float* tgt  = (const float*)d_in[1];
    float* out = (float*)d_out;

    char* ws = (char*)d_ws;
    int*   totals  = (int*)(ws + WS_TOTALS);
    int*   counts  = (int*)(ws + WS_COUNTS);
    int*   offsets = (int*)(ws + WS_OFFSETS);
    half8* Qfrag   = (half8*)(ws + WS_QFRAG);
    half8* Rfrag   = (half8*)(ws + WS_RFRAG);
    float* nqint   = (float*)(ws + WS_NQ);
    float* smin    = (float*)(ws + WS_SMIN);
    float* bsum    = (float*)(ws + WS_BSUM);

    k_init   <<<NCLOUD * PTS_PAD / 256, 256, 0, stream>>>(Qfrag, Rfrag, nqint);
    k_count  <<<NCLOUD * NCHUNK, 256, 0, stream>>>(pred, tgt, counts);
    k_scan   <<<NCLOUD,          256, 0, stream>>>(counts, offsets, totals);
    k_compact<<<NCLOUD * NCHUNK, 256, 0, stream>>>(pred, tgt, offsets, Qfrag, Rfrag, nqint);
    k_chamfer<<<NTASK * NQB * RSPLIT, 256, 0, stream>>>(Qfrag, Rfrag, smin);
    k_reduce <<<NTASK * NRB,     256, 0, stream>>>(nqint, totals, smin, bsum);
    k_final  <<<1, 1, 0, stream>>>(bsum, totals, out);
}

// Round 5
// 48.344 us; speedup vs baseline: 2.1880x; 1.0635x over previous
//
#include <hip/hip_runtime.h>
#include <hip/hip_bf16.h>

// ChamferDistanceLoss via exact-integer f16 MFMA (32x32x16), operand-swapped:
//   A (rows, LDS-streamed)  = refs    enc [rd, rh, rw, nr>>3, nr&7, 0,0,0]
//   B (cols, register-held) = queries enc [-2qd, -2qh, -2qw, 8, 1, 0,0,0]
// s = nr - 2 q.r exact (f16 operands are exact small ints, fp32 products exact).
// Lane's D col = one query -> per-lane scalar min accumulator (red16).
// MFMA dests pinned to VGPRs via asm("":"+v") to avoid v_accvgpr_read storms.
// min commutes with +nq; scale by (2/63)^2 at the end.

#define NVOX      262144
#define NCHUNK    256
#define MAXPTS    10000
#define PTS_PAD   10240
#define NCLOUD    8
#define NTASK     8
#define NRB       40         // reduce blocks per task
#define QPB       512        // queries per chamfer block (4 waves x 128)
#define NQB       20         // query blocks per task
#define RSPLIT    8          // ref splits per task
#define RLEN      1280       // refs per split
#define CH_REFS   640        // refs staged per LDS chunk (10 KB)
#define CH_STEPS  10         // 64-ref steps per chunk
#define NCH       2          // chunks per split
#define SCALE     (2.0f/63.0f)

typedef _Float16 half8  __attribute__((ext_vector_type(8)));
typedef float    f32x16 __attribute__((ext_vector_type(16)));

// ---------------- workspace layout (bytes) ----------------
#define WS_TOTALS   0           // 8 ints
#define WS_COUNTS   1024        // 8*256 ints
#define WS_OFFSETS  16384       // 8*256 ints
#define WS_QFRAG    32768       // 8*10240*16B = 1310720
#define WS_RFRAG    1343488     // 8*10240*16B = 1310720
#define WS_NQ       2654208     // 8*10240 f32 = 327680
#define WS_SMIN     2981888     // 8*8*10240 f32 = 2621440
#define WS_BSUM     5603328     // 8*40 f32

__device__ __forceinline__ const float* cloud_src(const float* pred, const float* tgt, int cloud) {
    const float* base = (cloud & 1) ? tgt : pred;
    return base + (size_t)(cloud >> 1) * NVOX;
}

// ---- Kernel 1: per-chunk active counts (+ pad init, merged) ----------------
__global__ void k_count(const float* __restrict__ pred, const float* __restrict__ tgt,
                        int* __restrict__ counts,
                        half8* __restrict__ Qfrag, half8* __restrict__ Rfrag,
                        float* __restrict__ nqint) {
    int gi = blockIdx.x * 256 + threadIdx.x;
    if (gi < NCLOUD * PTS_PAD) {   // init pads: overwritten for rank<total by k_compact
        half8 zq = {0, 0, 0, 0, 0, 0, 0, 0};                // pad query: s=0 (masked later)
        half8 zr = {0, 0, 0, (_Float16)4096, 0, 0, 0, 0};   // pad ref: s=8*4096=32768 > any real
        Qfrag[gi] = zq;
        Rfrag[gi] = zr;
        nqint[gi] = 0.f;
    }
    int cloud = blockIdx.x >> 8;
    int chunk = blockIdx.x & 255;
    int t = threadIdx.x;
    const float* src = cloud_src(pred, tgt, cloud) + chunk * 1024;
    float4 v = reinterpret_cast<const float4*>(src)[t];
    int cnt = (v.x > 0.5f) + (v.y > 0.5f) + (v.z > 0.5f) + (v.w > 0.5f);
    __shared__ int s[256];
    s[t] = cnt; __syncthreads();
    for (int o = 128; o > 0; o >>= 1) {
        if (t < o) s[t] += s[t + o];
        __syncthreads();
    }
    if (t == 0) counts[cloud * NCHUNK + chunk] = s[0];
}

// ---- Kernel 2: exclusive scan of chunk counts per cloud --------------------
__global__ void k_scan(const int* __restrict__ counts, int* __restrict__ offsets,
                       int* __restrict__ totals) {
    int cloud = blockIdx.x;
    int t = threadIdx.x;
    int c = counts[cloud * NCHUNK + t];
    __shared__ int s[256];
    s[t] = c; __syncthreads();
    for (int o = 1; o < 256; o <<= 1) {
        int v = (t >= o) ? s[t - o] : 0;
        __syncthreads();
        s[t] += v;
        __syncthreads();
    }
    offsets[cloud * NCHUNK + t] = s[t] - c;
    if (t == 255) totals[cloud] = s[255];
}

// ---- Kernel 3: ordered compaction -> Q/R fragments + nq --------------------
__global__ void k_compact(const float* __restrict__ pred, const float* __restrict__ tgt,
                          const int* __restrict__ offsets,
                          half8* __restrict__ Qfrag, half8* __restrict__ Rfrag,
                          float* __restrict__ nqint) {
    int cloud = blockIdx.x >> 8;
    int chunk = blockIdx.x & 255;
    int t = threadIdx.x;
    const float* src = cloud_src(pred, tgt, cloud) + chunk * 1024;
    float4 v = reinterpret_cast<const float4*>(src)[t];
    int f0 = v.x > 0.5f, f1 = v.y > 0.5f, f2 = v.z > 0.5f, f3 = v.w > 0.5f;
    int cnt = f0 + f1 + f2 + f3;
    __shared__ int s[256];
    s[t] = cnt; __syncthreads();
    for (int o = 1; o < 256; o <<= 1) {
        int x = (t >= o) ? s[t - o] : 0;
        __syncthreads();
        s[t] += x;
        __syncthreads();
    }
    int rank = offsets[cloud * NCHUNK + chunk] + (s[t] - cnt);
    int eidx = chunk * 1024 + t * 4;
    int flags[4] = {f0, f1, f2, f3};
    size_t base = (size_t)cloud * PTS_PAD;
    #pragma unroll
    for (int e = 0; e < 4; ++e) {
        if (flags[e]) {
            if (rank < MAXPTS) {
                int idx = eidx + e;
                int d = idx >> 12, h = (idx >> 6) & 63, w = idx & 63;
                int nr = d * d + h * h + w * w;
                half8 Q = {(_Float16)(-2 * d), (_Float16)(-2 * h), (_Float16)(-2 * w),
                           (_Float16)8, (_Float16)1, 0, 0, 0};
                half8 R = {(_Float16)d, (_Float16)h, (_Float16)w,
                           (_Float16)(nr >> 3), (_Float16)(nr & 7), 0, 0, 0};
                Qfrag[base + rank] = Q;
                Rfrag[base + rank] = R;
                nqint[base + rank] = (float)nr;
            }
            rank++;
        }
    }
}

// ---- min3-shaped reduce of one f32x16 + carry ------------------------------
__device__ __forceinline__ float red16(f32x16 d, float m) {
    float t0 = fminf(fminf(d[0], d[1]), d[2]);
    float t1 = fminf(fminf(d[3], d[4]), d[5]);
    float t2 = fminf(fminf(d[6], d[7]), d[8]);
    float t3 = fminf(fminf(d[9], d[10]), d[11]);
    float t4 = fminf(fminf(d[12], d[13]), d[14]);
    float t5 = fminf(d[15], m);
    float u0 = fminf(fminf(t0, t1), t2);
    float u1 = fminf(fminf(t3, t4), t5);
    return fminf(u0, u1);
}

#define MFMA_MIN(aa, bb, mm)                                                      \
    do {                                                                          \
        f32x16 d_ = __builtin_amdgcn_mfma_f32_32x32x16_f16((aa), (bb), cz, 0, 0, 0); \
        asm("" : "+v"(d_));                                                       \
        (mm) = red16(d_, (mm));                                                   \
    } while (0)

// ---- Kernel 4: chamfer min via 32x32x16 MFMA, refs-as-rows ------------------
// grid = NTASK*NQB*RSPLIT = 1280 blocks, 256 thr (4 waves). Wave holds 128
// queries (4 B col-tiles); streams RLEN refs as A row-tiles from LDS chunks.
// Per 64-ref step: 2 ds_read_b128 + 8 MFMA + ~72 min3 (covers 128q x 64r/wave).
__global__ __launch_bounds__(256, 4) void k_chamfer(const half8* __restrict__ Qfrag,
                                                    const half8* __restrict__ Rfrag,
                                                    float* __restrict__ smin) {
    int task = blockIdx.x / (NQB * RSPLIT);
    int rem  = blockIdx.x % (NQB * RSPLIT);
    int qb   = rem / RSPLIT;
    int rs   = rem % RSPLIT;
    int b = task >> 1, dir = task & 1;
    int qc = 2 * b + dir;
    int rc = 2 * b + (dir ^ 1);
    int tid = threadIdx.x, wave = tid >> 6, lane = tid & 63;

    __shared__ float4 ldsv[CH_REFS];   // 10 KB
    char* lds = (char*)ldsv;

    int qbase = qb * QPB + wave * 128;
    half8 zero8 = {0, 0, 0, 0, 0, 0, 0, 0};
    half8 bq0 = zero8, bq1 = zero8, bq2 = zero8, bq3 = zero8;
    if (lane < 32) {   // lanes>=32 supply k=8..15: zero nullifies aliased A reads
        const half8* qp = Qfrag + (size_t)qc * PTS_PAD + qbase + lane;
        bq0 = qp[0]; bq1 = qp[32]; bq2 = qp[64]; bq3 = qp[96];
    }
    float m0 = 1e30f, m1 = 1e30f, m2 = 1e30f, m3 = 1e30f;
    f32x16 cz;
    #pragma unroll
    for (int e = 0; e < 16; ++e) cz[e] = 0.f;

    const float4* Rsrc = (const float4*)(Rfrag + (size_t)rc * PTS_PAD + rs * RLEN);
    const char* rdbase = lds + (lane & 31) * 16;

    for (int c = 0; c < NCH; ++c) {
        __syncthreads();
        const float4* src = Rsrc + c * CH_REFS;
        for (int i = tid; i < CH_REFS; i += 256) ldsv[i] = src[i];
        __syncthreads();
        #pragma unroll 2
        for (int t = 0; t < CH_STEPS; ++t) {
            half8 a0 = *(const half8*)(rdbase + t * 1024);
            half8 a1 = *(const half8*)(rdbase + t * 1024 + 512);
            MFMA_MIN(a0, bq0, m0);
            MFMA_MIN(a1, bq0, m0);
            MFMA_MIN(a0, bq1, m1);
            MFMA_MIN(a1, bq1, m1);
            MFMA_MIN(a0, bq2, m2);
            MFMA_MIN(a1, bq2, m2);
            MFMA_MIN(a0, bq3, m3);
            MFMA_MIN(a1, bq3, m3);
        }
    }

    // lane L and L+32 hold complementary ref-rows of query col (lane&31)
    m0 = fminf(m0, __shfl_xor(m0, 32));
    m1 = fminf(m1, __shfl_xor(m1, 32));
    m2 = fminf(m2, __shfl_xor(m2, 32));
    m3 = fminf(m3, __shfl_xor(m3, 32));
    if (lane < 32) {
        float* outp = smin + ((size_t)task * RSPLIT + rs) * PTS_PAD + qbase + lane;
        outp[0]  = m0;
        outp[32] = m1;
        outp[64] = m2;
        outp[96] = m3;
    }
}

// ---- Kernel 5: min over splits, add nq, scale, clamp, masked block sum -----
__global__ void k_reduce(const float* __restrict__ nqint, const int* __restrict__ totals,
                         const float* __restrict__ smin, float* __restrict__ bsum) {
    int task = blockIdx.x / NRB;
    int rb   = blockIdx.x % NRB;
    int tid  = threadIdx.x;
    int qi   = rb * 256 + tid;
    int qc   = 2 * (task >> 1) + (task & 1);
    int countQ = min(totals[qc], MAXPTS);

    const float SC2 = SCALE * SCALE;
    float contrib = 0.f;
    if (qi < countQ) {
        const float* s = smin + (size_t)task * RSPLIT * PTS_PAD + qi;
        float m = fminf(fminf(s[0 * PTS_PAD], s[1 * PTS_PAD]),
                        fminf(s[2 * PTS_PAD], s[3 * PTS_PAD]));
        m = fminf(m, fminf(fminf(s[4 * PTS_PAD], s[5 * PTS_PAD]),
                           fminf(s[6 * PTS_PAD], s[7 * PTS_PAD])));
        float nq = nqint[(size_t)qc * PTS_PAD + qi];
        contrib = fmaxf((nq + m) * SC2, 0.f);
    }
    __shared__ float sb[256];
    sb[tid] = contrib; __syncthreads();
    for (int o = 128; o > 0; o >>= 1) {
        if (tid < o) sb[tid] += sb[tid + o];
        __syncthreads();
    }
    if (tid == 0) bsum[task * NRB + rb] = sb[0];
}

// ---- Kernel 6: deterministic final combine ---------------------------------
__global__ void k_final(const float* __restrict__ bsum, const int* __restrict__ totals,
                        float* __restrict__ out) {
    float total = 0.f, nv = 0.f;
    for (int b = 0; b < 4; ++b) {
        float s1 = 0.f, s2 = 0.f;
        for (int i = 0; i < NRB; ++i) {
            s1 += bsum[(2 * b) * NRB + i];
            s2 += bsum[(2 * b + 1) * NRB + i];
        }
        int c1 = min(totals[2 * b], MAXPTS);
        int c2 = min(totals[2 * b + 1], MAXPTS);
        float cd = s1 / fmaxf((float)c1, 1.f) + s2 / fmaxf((float)c2, 1.f);
        if (c1 > 0 && c2 > 0) { total += cd; nv += 1.f; }
    }
    out[0] = (nv > 0.f) ? total / nv : 0.f;
}

extern "C" void kernel_launch(void* const* d_in, const int* in_sizes, int n_in,
                              void* d_out, int out_size, void* d_ws, size_t ws_size,
                              hipStream_t stream) {
    const float* pred = (const float*)d_in[0];
    const float* tgt  = (const float*)d_in[1];
    float* out = (float*)d_out;

    char* ws = (char*)d_ws;
    int*   totals  = (int*)(ws + WS_TOTALS);
    int*   counts  = (int*)(ws + WS_COUNTS);
    int*   offsets = (int*)(ws + WS_OFFSETS);
    half8* Qfrag   = (half8*)(ws + WS_QFRAG);
    half8* Rfrag   = (half8*)(ws + WS_RFRAG);
    float* nqint   = (float*)(ws + WS_NQ);
    float* smin    = (float*)(ws + WS_SMIN);
    float* bsum    = (float*)(ws + WS_BSUM);

    k_count  <<<NCLOUD * NCHUNK, 256, 0, stream>>>(pred, tgt, counts, Qfrag, Rfrag, nqint);
    k_scan   <<<NCLOUD,          256, 0, stream>>>(counts, offsets, totals);
    k_compact<<<NCLOUD * NCHUNK, 256, 0, stream>>>(pred, tgt, offsets, Qfrag, Rfrag, nqint);
    k_chamfer<<<NTASK * NQB * RSPLIT, 256, 0, stream>>>(Qfrag, Rfrag, smin);
    k_reduce <<<NTASK * NRB,     256, 0, stream>>>(nqint, totals, smin, bsum);
    k_final  <<<1, 1, 0, stream>>>(bsum, totals, out);
}